// Round 4
// baseline (439.879 us; speedup 1.0000x reference)
//
#include <hip/hip_runtime.h>
#include <stdint.h>

#define D_DIM 256
#define BI 128       // i-rows per block
#define TJ 128       // j-tile
#define CHUNK 2048   // j per block
#define KSTRIDE 136  // Ksm row stride (ushorts): 16B-aligned rows

typedef unsigned short ushort_t;
typedef __attribute__((ext_vector_type(8))) short bf16x8;   // 8 bf16 = 4 VGPRs
typedef __attribute__((ext_vector_type(4))) float f32x4;

__device__ __forceinline__ unsigned short f2bf(float f) {
  union { float f; unsigned u; } x; x.f = f;
  unsigned r = x.u + 0x7FFFu + ((x.u >> 16) & 1u);  // round-nearest-even
  return (unsigned short)(r >> 16);
}

__device__ __forceinline__ float fast_sqrt(float x) {
#if __has_builtin(__builtin_amdgcn_sqrtf)
  return __builtin_amdgcn_sqrtf(x);
#else
  return sqrtf(x);
#endif
}
__device__ __forceinline__ float fast_exp2(float x) {
#if __has_builtin(__builtin_amdgcn_exp2f)
  return __builtin_amdgcn_exp2f(x);
#else
  return exp2f(x);
#endif
}

// async global->LDS, 16B per lane. LDS dest = wave-uniform base + lane*16.
__device__ __forceinline__ void g2l16(const void* g, void* l) {
  __builtin_amdgcn_global_load_lds(
      (__attribute__((address_space(1))) void*)(uintptr_t)g,
      (__attribute__((address_space(3))) void*)(unsigned)(uintptr_t)l,
      16, 0, 0);
}

// ---------------- prep: cast fp32 -> bf16 rows + row norms (fp32-exact) ----------------
__global__ __launch_bounds__(256) void
prep_cast(const float* __restrict__ G, const float* __restrict__ P,
          ushort_t* __restrict__ Tb, float* __restrict__ nrm, int Bn)
{
  const int r = blockIdx.x, t = threadIdx.x;
  const float* src = (r < Bn) ? (G + (size_t)r * D_DIM)
                              : (P + (size_t)(r - Bn) * D_DIM);
  float v = src[t];
  Tb[(size_t)r * D_DIM + t] = f2bf(v);
  float s = v * v;
  #pragma unroll
  for (int o = 32; o > 0; o >>= 1) s += __shfl_down(s, o, 64);
  __shared__ float red[4];
  if ((t & 63) == 0) red[t >> 6] = s;
  __syncthreads();
  if (t == 0) nrm[r] = red[0] + red[1] + red[2] + red[3];
}

// ---------------- prep: transpose Tb (Ttot x 256) -> TT (256 x Ttot) ----------------
__global__ __launch_bounds__(256) void
prep_transpose(const ushort_t* __restrict__ Tb, ushort_t* __restrict__ TT, int Ttot)
{
  __shared__ ushort_t Ts[64][72];
  const int t = threadIdx.x;
  const int j0 = blockIdx.x * 64, d0 = blockIdx.y * 64;
  #pragma unroll
  for (int q = 0; q < 16; q++) {
    int idx = q * 256 + t;
    int jr = idx >> 6, dc = idx & 63;
    Ts[dc][jr] = Tb[(size_t)(j0 + jr) * D_DIM + d0 + dc];
  }
  __syncthreads();
  #pragma unroll
  for (int q = 0; q < 16; q++) {
    int idx = q * 256 + t;
    int dr = idx >> 6, jc = idx & 63;
    TT[(size_t)(d0 + dr) * Ttot + j0 + jc] = Ts[dr][jc];
  }
}

// ---------------- fused: S^T -> kv (LDS) -> O^T partials ----------------
// 512 thr / 8 waves. i-tile = 128; j-chunk = 2048 (16 tiles of 128).
// GEMM1 (S^T 128j x 128i): wave (wr=w>>2, wc=w&3) owns 64j x 32i; BK=64 via 2 panels.
// Epilogue: kv=exp(-dist/20) -> Ksm[i][j], rowsums in regs.
// GEMM2 (O^T 256d x 128i): wave (wd=w>>1, wi=w&1) owns 64d x 64i; acc across all tiles.
// End: rowsums -> atomicAdd(sg/sp); O^T -> coalesced f32x4 stores into Part[chunk].
__global__ __launch_bounds__(512, 4) void
fused_kernel(const ushort_t* __restrict__ Tb, const ushort_t* __restrict__ TT,
             const float* __restrict__ nrm, float* __restrict__ sg,
             float* __restrict__ sp, float* __restrict__ Part,
             int Bn, int Ttot)
{
  // Region (32 KB): GEMM1 = Asm panels [0),[4096) + Gsm panels [8192),[12288)
  //                 GEMM2 = TTsm panel0 [0..8192) (256 rows x 32), panel1 [8192..16384)
  __shared__ ushort_t Region[16384];
  __shared__ ushort_t Ksm[BI * KSTRIDE];   // 34 KB

  const int t = threadIdx.x;
  const int w = t >> 6, lane = t & 63;
  const int q = lane >> 4, c = lane & 15;
  const int wr = w >> 2, wc = w & 3;       // GEMM1
  const int wd = w >> 1, wi = w & 1;       // GEMM2
  const int i0 = blockIdx.x * BI;
  const int chunk0 = blockIdx.y * CHUNK;
  const bool gen = (chunk0 < Bn);

  const int srow = t >> 2;        // 0..127
  const int scol = (t & 3) * 8;   // 0,8,16,24

  f32x4 accO[4][4];
  #pragma unroll
  for (int m = 0; m < 4; m++)
    #pragma unroll
    for (int n = 0; n < 4; n++) accO[m][n] = (f32x4)0.f;
  float rs[2] = {0.f, 0.f};
  float ni[2];
  #pragma unroll
  for (int nt = 0; nt < 2; nt++) ni[nt] = nrm[i0 + wc * 32 + nt * 16 + c];

  for (int jt = 0; jt < CHUNK; jt += TJ) {
    const int j0 = chunk0 + jt;
    f32x4 acc1[4][2];
    #pragma unroll
    for (int m = 0; m < 4; m++)
      #pragma unroll
      for (int n = 0; n < 2; n++) acc1[m][n] = (f32x4)0.f;

    // ---- GEMM1: S^T over d = 256, BK=64 (2 panels of 32) ----
    #pragma unroll
    for (int k0 = 0; k0 < D_DIM; k0 += 64) {
      const ushort_t* a = Tb + (size_t)(j0 + srow) * D_DIM + k0 + scol;
      const ushort_t* g = Tb + (size_t)(i0 + srow) * D_DIM + k0 + scol;
      g2l16(a,      Region + t * 8);            // Asm p0
      g2l16(a + 32, Region + 4096 + t * 8);     // Asm p1
      g2l16(g,      Region + 8192 + t * 8);     // Gsm p0
      g2l16(g + 32, Region + 12288 + t * 8);    // Gsm p1
      __syncthreads();
      #pragma unroll
      for (int p = 0; p < 2; p++) {
        bf16x8 af[4], bf[2];
        #pragma unroll
        for (int mt = 0; mt < 4; mt++)
          af[mt] = *(const bf16x8*)&Region[p * 4096 + (wr * 64 + mt * 16 + c) * 32 + q * 8];
        #pragma unroll
        for (int nt = 0; nt < 2; nt++)
          bf[nt] = *(const bf16x8*)&Region[8192 + p * 4096 + (wc * 32 + nt * 16 + c) * 32 + q * 8];
        #pragma unroll
        for (int mt = 0; mt < 4; mt++)
          #pragma unroll
          for (int nt = 0; nt < 2; nt++)
            acc1[mt][nt] = __builtin_amdgcn_mfma_f32_16x16x32_bf16(af[mt], bf[nt], acc1[mt][nt], 0, 0, 0);
      }
      __syncthreads();
    }

    // ---- epilogue: kv = exp(-dist/20), rowsums, pack -> Ksm ----
    #pragma unroll
    for (int mt = 0; mt < 4; mt++) {
      const int jl = wr * 64 + mt * 16 + q * 4;      // local j of reg 0
      const int jb = j0 + jl;                        // global j
      const float4 njv = *(const float4*)&nrm[jb];
      const float nj[4] = {njv.x, njv.y, njv.z, njv.w};
      #pragma unroll
      for (int nt = 0; nt < 2; nt++) {
        const int il = wc * 32 + nt * 16 + c;
        const int ig = i0 + il;
        uint32_t pb[4];
        #pragma unroll
        for (int reg = 0; reg < 4; reg++) {
          float sq = fmaxf(ni[nt] + nj[reg] - 2.f * acc1[mt][nt][reg], 0.f);
          float dd = fast_sqrt(sq);
          float kv = fast_exp2(dd * -0.07213475204444817f);  // exp(-dd/20)
          if (gen && (jb + reg == ig)) kv = 0.f;
          rs[nt] += kv;
          union { float f; uint32_t u; } uu; uu.f = kv; pb[reg] = uu.u;
        }
        uint2 pk;  // truncating bf16 pack: 1 v_perm per pair
        pk.x = __builtin_amdgcn_perm(pb[1], pb[0], 0x07060302u);
        pk.y = __builtin_amdgcn_perm(pb[3], pb[2], 0x07060302u);
        *(uint2*)&Ksm[il * KSTRIDE + jl] = pk;
      }
    }
    __syncthreads();   // Ksm visible to all waves

    // ---- GEMM2: O^T += TT[d][j128] * kv, BK=64 (2 panels of 32) ----
    #pragma unroll
    for (int ks = 0; ks < TJ; ks += 64) {
      const ushort_t* t0 = TT + (size_t)srow * Ttot + j0 + ks + scol;
      g2l16(t0,                         Region + t * 8);           // p0 rows 0..127
      g2l16(t0 + (size_t)128 * Ttot,    Region + 4096 + t * 8);    // p0 rows 128..255
      g2l16(t0 + 32,                    Region + 8192 + t * 8);    // p1 rows 0..127
      g2l16(t0 + (size_t)128 * Ttot + 32, Region + 12288 + t * 8); // p1 rows 128..255
      __syncthreads();
      #pragma unroll
      for (int p = 0; p < 2; p++) {
        bf16x8 af[4], kf[4];
        #pragma unroll
        for (int mt = 0; mt < 4; mt++)
          af[mt] = *(const bf16x8*)&Region[p * 8192 + (wd * 64 + mt * 16 + c) * 32 + q * 8];
        #pragma unroll
        for (int nt = 0; nt < 4; nt++)
          kf[nt] = *(const bf16x8*)&Ksm[(wi * 64 + nt * 16 + c) * KSTRIDE + ks + p * 32 + q * 8];
        #pragma unroll
        for (int mt = 0; mt < 4; mt++)
          #pragma unroll
          for (int nt = 0; nt < 4; nt++)
            accO[mt][nt] = __builtin_amdgcn_mfma_f32_16x16x32_bf16(af[mt], kf[nt], accO[mt][nt], 0, 0, 0);
      }
      __syncthreads();
    }
  }

  // rowsum partials -> sg/sp (one atomic pass per block)
  float* S = gen ? sg : sp;
  #pragma unroll
  for (int nt = 0; nt < 2; nt++) {
    float r = rs[nt];
    r += __shfl_xor(r, 16, 64);
    r += __shfl_xor(r, 32, 64);
    if (lane < 16) atomicAdd(&S[i0 + wc * 32 + nt * 16 + lane], r);
  }
  // O^T partials -> Part[chunk][i][d], coalesced f32x4 (reg dim contiguous in d)
  float* Pdst = Part + (size_t)blockIdx.y * ((size_t)8192 * D_DIM);
  #pragma unroll
  for (int mt = 0; mt < 4; mt++)
    #pragma unroll
    for (int nt = 0; nt < 4; nt++) {
      const int d = wd * 64 + mt * 16 + q * 4;
      const int ig = i0 + wi * 64 + nt * 16 + c;
      *(f32x4*)&Pdst[(size_t)ig * D_DIM + d] = accO[mt][nt];
    }
}

// ---------------- combine: out = sg*sum(pos parts) - sp*sum(gen parts) ----------------
__global__ __launch_bounds__(256) void
combine_kernel(float* __restrict__ out, const float* __restrict__ Part,
               const float* __restrict__ sg, const float* __restrict__ sp)
{
  const int i = blockIdx.x, d = threadIdx.x;
  const size_t stride = (size_t)8192 * D_DIM;
  const float* p = Part + (size_t)i * D_DIM + d;
  float gsum = 0.f, psum = 0.f;
  #pragma unroll
  for (int cidx = 0; cidx < 4; cidx++) gsum += p[cidx * stride];
  #pragma unroll
  for (int cidx = 4; cidx < 8; cidx++) psum += p[cidx * stride];
  out[(size_t)i * D_DIM + d] = sg[i] * psum - sp[i] * gsum;
}

extern "C" void kernel_launch(void* const* d_in, const int* in_sizes, int n_in,
                              void* d_out, int out_size, void* d_ws, size_t ws_size,
                              hipStream_t stream)
{
  const float* G = (const float*)d_in[0];
  const float* P = (const float*)d_in[1];
  const int Bn = in_sizes[0] / D_DIM;   // 8192
  const int Xn = in_sizes[1] / D_DIM;   // 8192
  const int Ttot = Bn + Xn;             // 16384

  // workspace (~80.2 MiB)
  uint8_t* ws = (uint8_t*)d_ws;
  size_t off = 0;
  ushort_t* Tb = (ushort_t*)(ws + off); off += (size_t)Ttot * D_DIM * 2;   // 8 MiB
  ushort_t* TT = (ushort_t*)(ws + off); off += (size_t)Ttot * D_DIM * 2;   // 8 MiB
  float* nrm = (float*)(ws + off); off += (size_t)Ttot * 4;
  float* sg  = (float*)(ws + off); off += (size_t)Bn * 4;
  float* sp  = (float*)(ws + off); off += (size_t)Bn * 4;
  off = (off + 255) & ~(size_t)255;
  float* Part = (float*)(ws + off); off += (size_t)8 * Bn * D_DIM * 4;     // 64 MiB
  if (ws_size < off) return;  // clean-fail signature if ws too small

  hipMemsetAsync(sg, 0, (size_t)Bn * 2 * sizeof(float), stream);  // sg+sp contiguous

  prep_cast<<<Ttot, 256, 0, stream>>>(G, P, Tb, nrm, Bn);
  prep_transpose<<<dim3(Ttot / 64, D_DIM / 64), 256, 0, stream>>>(Tb, TT, Ttot);
  fused_kernel<<<dim3(Bn / BI, Ttot / CHUNK), 512, 0, stream>>>(
      Tb, TT, nrm, sg, sp, Part, Bn, Ttot);
  combine_kernel<<<Bn, 256, 0, stream>>>((float*)d_out, Part, sg, sp);
}

// Round 5
// 303.009 us; speedup vs baseline: 1.4517x; 1.4517x over previous
//
#include <hip/hip_runtime.h>
#include <stdint.h>

#define D_DIM 256
#define BI 128       // i-rows per block
#define TJ 128       // j-tile
#define CHUNK 2048   // j per block
#define KSTRIDE 136  // Ksm row stride (ushorts), 16B-aligned rows

typedef unsigned short ushort_t;
typedef __attribute__((ext_vector_type(8))) short bf16x8;   // 8 bf16 = 4 VGPRs
typedef __attribute__((ext_vector_type(4))) float f32x4;

__device__ __forceinline__ unsigned short f2bf(float f) {
  union { float f; unsigned u; } x; x.f = f;
  unsigned r = x.u + 0x7FFFu + ((x.u >> 16) & 1u);  // round-nearest-even
  return (unsigned short)(r >> 16);
}

__device__ __forceinline__ float fast_sqrt(float x) {
#if __has_builtin(__builtin_amdgcn_sqrtf)
  return __builtin_amdgcn_sqrtf(x);
#else
  return sqrtf(x);
#endif
}
__device__ __forceinline__ float fast_exp2(float x) {
#if __has_builtin(__builtin_amdgcn_exp2f)
  return __builtin_amdgcn_exp2f(x);
#else
  return exp2f(x);
#endif
}

// async global->LDS, 16B per lane. LDS dest must be (wave-uniform base) + lane*16;
// any expression of the form Base + t*8 (ushorts) satisfies this.
__device__ __forceinline__ void g2l16(const void* g, void* l) {
  __builtin_amdgcn_global_load_lds(
      (__attribute__((address_space(1))) void*)(uintptr_t)g,
      (__attribute__((address_space(3))) void*)(unsigned)(uintptr_t)l,
      16, 0, 0);
}

// ---------------- prep: cast fp32 -> bf16 rows + row norms (fp32-exact) ----------------
__global__ __launch_bounds__(256) void
prep_cast(const float* __restrict__ G, const float* __restrict__ P,
          ushort_t* __restrict__ Tb, float* __restrict__ nrm, int Bn)
{
  const int r = blockIdx.x, t = threadIdx.x;
  const float* src = (r < Bn) ? (G + (size_t)r * D_DIM)
                              : (P + (size_t)(r - Bn) * D_DIM);
  float v = src[t];
  Tb[(size_t)r * D_DIM + t] = f2bf(v);
  float s = v * v;
  #pragma unroll
  for (int o = 32; o > 0; o >>= 1) s += __shfl_down(s, o, 64);
  __shared__ float red[4];
  if ((t & 63) == 0) red[t >> 6] = s;
  __syncthreads();
  if (t == 0) nrm[r] = red[0] + red[1] + red[2] + red[3];
}

// ---------------- prep: transpose Tb (Ttot x 256) -> TT (256 x Ttot) ----------------
__global__ __launch_bounds__(256) void
prep_transpose(const ushort_t* __restrict__ Tb, ushort_t* __restrict__ TT, int Ttot)
{
  __shared__ ushort_t Ts[64][72];
  const int t = threadIdx.x;
  const int j0 = blockIdx.x * 64, d0 = blockIdx.y * 64;
  #pragma unroll
  for (int q = 0; q < 16; q++) {
    int idx = q * 256 + t;
    int jr = idx >> 6, dc = idx & 63;
    Ts[dc][jr] = Tb[(size_t)(j0 + jr) * D_DIM + d0 + dc];
  }
  __syncthreads();
  #pragma unroll
  for (int q = 0; q < 16; q++) {
    int idx = q * 256 + t;
    int dr = idx >> 6, jc = idx & 63;
    TT[(size_t)(d0 + dr) * Ttot + j0 + jc] = Ts[dr][jc];
  }
}

// ---------------- fused: S^T -> kv (LDS) -> O^T partials ----------------
// 1024 thr / 16 waves / 1 block per CU. i-tile 128; chunk 2048 = 16 tiles of 128.
// LDS: Gsm 64KB resident (i-tile, full K, swizzled) + Region 32KB (A / TT staging)
//      + Ksm 34KB. Swizzled layout: [sub64][row][col64 ^ (row&7)*8].
// GEMM1: S^T[j128][i128]; wave (wj=w>>2, wcol=w&3) owns 32j x 32i -> acc1[2][2].
// GEMM2: O^T[d256][i128]; wave (wd2=w>>1, wi=w&1) owns 16d(per half) x 64i
//        -> accO[2(half)][4] = 32 regs. Total acc 48 regs -> fits 128-reg cap.
__global__ __launch_bounds__(1024, 4) void
fused_kernel(const ushort_t* __restrict__ Tb, const ushort_t* __restrict__ TT,
             const float* __restrict__ nrm, float* __restrict__ sg,
             float* __restrict__ sp, float* __restrict__ Part,
             int Bn, int Ttot)
{
  __shared__ ushort_t Gsm[4 * 8192];     // 64 KB: [kq(64-wide)][row i][64 swz]
  __shared__ ushort_t Region[2 * 8192];  // 32 KB: [sub][row][64 swz]
  __shared__ ushort_t Ksm[128 * KSTRIDE];// 34 KB: kv[i][j] (+pad)

  const int t = threadIdx.x;
  const int w = t >> 6, lane = t & 63;
  const int q = lane >> 4, c = lane & 15;
  const int wj = w >> 2, wcol = w & 3;   // GEMM1 map
  const int wd2 = w >> 1, wi = w & 1;    // GEMM2 map
  const int i0 = blockIdx.x * BI;
  const int chunk0 = blockIdx.y * CHUNK;
  const bool gen = (chunk0 < Bn);
  const int swz = (c & 7) * 8;           // reader-side XOR (per-lane constant)

  // staging map: one issue = 128 rows x 64 swizzled ushorts (16 KB)
  const int srow = t >> 3;               // 0..127
  const int scol = ((t & 7) * 8) ^ ((srow & 7) * 8);  // source col within 64

  // ---- stage resident G (i-tile, full K=256) ----
  {
    const ushort_t* gsrc = Tb + (size_t)(i0 + srow) * D_DIM;
    #pragma unroll
    for (int kq = 0; kq < 4; kq++)
      g2l16(gsrc + kq * 64 + scol, Gsm + kq * 8192 + t * 8);
  }

  f32x4 accO[2][4];
  #pragma unroll
  for (int h = 0; h < 2; h++)
    #pragma unroll
    for (int n = 0; n < 4; n++) accO[h][n] = (f32x4)0.f;
  float rs[2] = {0.f, 0.f};
  float ni[2];
  #pragma unroll
  for (int nt = 0; nt < 2; nt++) ni[nt] = nrm[i0 + wcol * 32 + nt * 16 + c];

  __syncthreads();   // Gsm ready

  for (int jt = 0; jt < CHUNK; jt += TJ) {
    const int j0g = chunk0 + jt;
    f32x4 acc1[2][2];
    #pragma unroll
    for (int m = 0; m < 2; m++)
      #pragma unroll
      for (int n = 0; n < 2; n++) acc1[m][n] = (f32x4)0.f;

    // ---- GEMM1: S^T over K=256, two 128-k stages ----
    #pragma unroll
    for (int s = 0; s < 2; s++) {
      const ushort_t* asrc = Tb + (size_t)(j0g + srow) * D_DIM + s * 128;
      g2l16(asrc + scol,      Region + t * 8);
      g2l16(asrc + 64 + scol, Region + 8192 + t * 8);
      __syncthreads();
      #pragma unroll
      for (int p = 0; p < 4; p++) {
        const int colA = (((p & 1) * 32) + q * 8) ^ swz;
        bf16x8 af[2], bf[2];
        #pragma unroll
        for (int mt = 0; mt < 2; mt++)
          af[mt] = *(const bf16x8*)&Region[(p >> 1) * 8192 + (wj * 32 + mt * 16 + c) * 64 + colA];
        #pragma unroll
        for (int nt = 0; nt < 2; nt++)
          bf[nt] = *(const bf16x8*)&Gsm[(s * 2 + (p >> 1)) * 8192 + (wcol * 32 + nt * 16 + c) * 64 + colA];
        #pragma unroll
        for (int mt = 0; mt < 2; mt++)
          #pragma unroll
          for (int nt = 0; nt < 2; nt++)
            acc1[mt][nt] = __builtin_amdgcn_mfma_f32_16x16x32_bf16(af[mt], bf[nt], acc1[mt][nt], 0, 0, 0);
      }
      __syncthreads();   // Region free for next stage / TT
    }

    // ---- issue TT half-0 staging now; it overlaps the epilogue VALU ----
    {
      const ushort_t* tsrc = TT + (size_t)srow * Ttot + j0g;
      g2l16(tsrc + scol,      Region + t * 8);
      g2l16(tsrc + 64 + scol, Region + 8192 + t * 8);
    }

    // ---- epilogue: kv = exp(-dist/20), rowsums, pack -> Ksm ----
    #pragma unroll
    for (int mt = 0; mt < 2; mt++) {
      const int jl = wj * 32 + mt * 16 + q * 4;   // local j of reg 0
      const int jb = j0g + jl;                    // global j
      const float4 njv = *(const float4*)&nrm[jb];
      const float nj[4] = {njv.x, njv.y, njv.z, njv.w};
      #pragma unroll
      for (int nt = 0; nt < 2; nt++) {
        const int il = wcol * 32 + nt * 16 + c;
        const int ig = i0 + il;
        uint32_t pb[4];
        #pragma unroll
        for (int reg = 0; reg < 4; reg++) {
          float sq = fmaxf(ni[nt] + nj[reg] - 2.f * acc1[mt][nt][reg], 0.f);
          float dd = fast_sqrt(sq);
          float kv = fast_exp2(dd * -0.07213475204444817f);  // exp(-dd/20)
          if (gen && (jb + reg == ig)) kv = 0.f;
          rs[nt] += kv;
          union { float f; uint32_t u; } uu; uu.f = kv; pb[reg] = uu.u;
        }
        uint2 pk;  // truncating bf16 pack: 1 v_perm per pair
        pk.x = __builtin_amdgcn_perm(pb[1], pb[0], 0x07060302u);
        pk.y = __builtin_amdgcn_perm(pb[3], pb[2], 0x07060302u);
        *(uint2*)&Ksm[il * KSTRIDE + jl] = pk;
      }
    }
    __syncthreads();   // TT-h0 staged + Ksm visible

    // ---- GEMM2 half 0: accO[0] += TT[0:128][j] * kv ----
    #pragma unroll
    for (int p = 0; p < 4; p++) {
      const int colA = (((p & 1) * 32) + q * 8) ^ swz;
      bf16x8 af2 = *(const bf16x8*)&Region[(p >> 1) * 8192 + (wd2 * 16 + c) * 64 + colA];
      bf16x8 kf[4];
      #pragma unroll
      for (int nt = 0; nt < 4; nt++)
        kf[nt] = *(const bf16x8*)&Ksm[(wi * 64 + nt * 16 + c) * KSTRIDE + p * 32 + q * 8];
      #pragma unroll
      for (int nt = 0; nt < 4; nt++)
        accO[0][nt] = __builtin_amdgcn_mfma_f32_16x16x32_bf16(af2, kf[nt], accO[0][nt], 0, 0, 0);
    }
    __syncthreads();   // done reading Region

    // ---- stage TT half 1 ----
    {
      const ushort_t* tsrc = TT + (size_t)(128 + srow) * Ttot + j0g;
      g2l16(tsrc + scol,      Region + t * 8);
      g2l16(tsrc + 64 + scol, Region + 8192 + t * 8);
    }
    __syncthreads();

    // ---- GEMM2 half 1 ----
    #pragma unroll
    for (int p = 0; p < 4; p++) {
      const int colA = (((p & 1) * 32) + q * 8) ^ swz;
      bf16x8 af2 = *(const bf16x8*)&Region[(p >> 1) * 8192 + (wd2 * 16 + c) * 64 + colA];
      bf16x8 kf[4];
      #pragma unroll
      for (int nt = 0; nt < 4; nt++)
        kf[nt] = *(const bf16x8*)&Ksm[(wi * 64 + nt * 16 + c) * KSTRIDE + p * 32 + q * 8];
      #pragma unroll
      for (int nt = 0; nt < 4; nt++)
        accO[1][nt] = __builtin_amdgcn_mfma_f32_16x16x32_bf16(af2, kf[nt], accO[1][nt], 0, 0, 0);
    }
    __syncthreads();   // Region free for next tile's A staging
  }

  // rowsum partials -> sg/sp
  float* S = gen ? sg : sp;
  #pragma unroll
  for (int nt = 0; nt < 2; nt++) {
    float r = rs[nt];
    r += __shfl_xor(r, 16, 64);
    r += __shfl_xor(r, 32, 64);
    if (lane < 16) atomicAdd(&S[i0 + wcol * 32 + nt * 16 + lane], r);
  }
  // O^T partials -> Part[chunk][i][d] (f32x4, 16B aligned)
  float* Pdst = Part + (size_t)blockIdx.y * ((size_t)8192 * D_DIM);
  #pragma unroll
  for (int h = 0; h < 2; h++)
    #pragma unroll
    for (int nt = 0; nt < 4; nt++) {
      const int d = h * 128 + wd2 * 16 + q * 4;
      const int ig = i0 + wi * 64 + nt * 16 + c;
      *(f32x4*)&Pdst[(size_t)ig * D_DIM + d] = accO[h][nt];
    }
}

// ---------------- combine: out = sg*sum(pos parts) - sp*sum(gen parts) ----------------
__global__ __launch_bounds__(256) void
combine_kernel(float* __restrict__ out, const float* __restrict__ Part,
               const float* __restrict__ sg, const float* __restrict__ sp)
{
  const int i = blockIdx.x, d = threadIdx.x;
  const size_t stride = (size_t)8192 * D_DIM;
  const float* p = Part + (size_t)i * D_DIM + d;
  float gsum = 0.f, psum = 0.f;
  #pragma unroll
  for (int cidx = 0; cidx < 4; cidx++) gsum += p[cidx * stride];
  #pragma unroll
  for (int cidx = 4; cidx < 8; cidx++) psum += p[cidx * stride];
  out[(size_t)i * D_DIM + d] = sg[i] * psum - sp[i] * gsum;
}

extern "C" void kernel_launch(void* const* d_in, const int* in_sizes, int n_in,
                              void* d_out, int out_size, void* d_ws, size_t ws_size,
                              hipStream_t stream)
{
  const float* G = (const float*)d_in[0];
  const float* P = (const float*)d_in[1];
  const int Bn = in_sizes[0] / D_DIM;   // 8192
  const int Xn = in_sizes[1] / D_DIM;   // 8192
  const int Ttot = Bn + Xn;             // 16384

  // workspace (~80.2 MiB)
  uint8_t* ws = (uint8_t*)d_ws;
  size_t off = 0;
  ushort_t* Tb = (ushort_t*)(ws + off); off += (size_t)Ttot * D_DIM * 2;   // 8 MiB
  ushort_t* TT = (ushort_t*)(ws + off); off += (size_t)Ttot * D_DIM * 2;   // 8 MiB
  float* nrm = (float*)(ws + off); off += (size_t)Ttot * 4;
  float* sg  = (float*)(ws + off); off += (size_t)Bn * 4;
  float* sp  = (float*)(ws + off); off += (size_t)Bn * 4;
  off = (off + 255) & ~(size_t)255;
  float* Part = (float*)(ws + off); off += (size_t)8 * Bn * D_DIM * 4;     // 64 MiB
  if (ws_size < off) return;  // clean-fail signature if ws too small

  hipMemsetAsync(sg, 0, (size_t)Bn * 2 * sizeof(float), stream);  // sg+sp contiguous

  prep_cast<<<Ttot, 256, 0, stream>>>(G, P, Tb, nrm, Bn);
  prep_transpose<<<dim3(Ttot / 64, D_DIM / 64), 256, 0, stream>>>(Tb, TT, Ttot);
  fused_kernel<<<dim3(Bn / BI, Ttot / CHUNK), 1024, 0, stream>>>(
      Tb, TT, nrm, sg, sp, Part, Bn, Ttot);
  combine_kernel<<<Bn, 256, 0, stream>>>((float*)d_out, Part, sg, sp);
}